// Round 5
// 33.029 us; speedup vs baseline: 1.0018x; 1.0018x over previous
//
#include <hip/hip_runtime.h>
#include <math.h>

typedef _Float16 half8 __attribute__((ext_vector_type(8)));
typedef float floatx16 __attribute__((ext_vector_type(16)));
typedef unsigned int uintx4 __attribute__((ext_vector_type(4)));

#define EPSV 1e-5f

// ---- workspace layout (bytes) ----
// 12 chunks of 14336 B, each = 6 w1-frags (6 KB) + 8 w2-frags (8 KB).
// Every frag = 64 lanes x 16 B in EXACT per-lane read order; main kernel
// reads fragments DIRECTLY from global (L1/L2-resident) — no LDS at all.
// R1-R4 lesson: every restructuring of the lane data flow (LDS staging in 3
// forms, and even a bitwise-equivalent single-m-tile remap) produced distinct
// deterministic wrong results. This round: R0 VERBATIM + provably-bijective
// block-ID swizzle only — a discriminating experiment for env vs model.
#define CHUNK_BYTES 14336
#define OFF_TILES 0
#define OFF_W3    (12 * CHUNK_BYTES)     // 172032 : 4 frags x 1 KB (w3 padded to 32 rows)
#define OFF_T2    (OFF_W3 + 4096)        // 64 f32 folded BN2 shift
#define OFF_OTAB  (OFF_T2 + 256)         // 29x4 f32 embedding-MLP table

// manual RTE f16 pack — HW-verified R5-R7; do NOT swap for cvt_pkrtz (R8 ERRATA)
__device__ __forceinline__ unsigned pk2(float a, float b) {
  _Float16 ha = (_Float16)a, hb = (_Float16)b;
  return (unsigned)__builtin_bit_cast(unsigned short, ha) |
         ((unsigned)__builtin_bit_cast(unsigned short, hb) << 16);
}
__device__ __forceinline__ void plswap(unsigned &a, unsigned &b) {
  asm volatile("v_permlane32_swap_b32 %0, %1" : "+v"(a), "+v"(b));
}
// Build GEMM2 B-operand fragment (k-chunk word q = elems hi*8+2q,+1) from 8
// C-layout values (rows (r&3)+8*(r>>2)+4*hi), applying relu + f16 cast.
// HW-verified R5-R7.
__device__ __forceinline__ half8 mk_bfrag(float v0, float v1, float v2, float v3,
                                          float v4, float v5, float v6, float v7) {
  unsigned r0 = pk2(fmaxf(v0, 0.f), fmaxf(v1, 0.f));
  unsigned r1 = pk2(fmaxf(v2, 0.f), fmaxf(v3, 0.f));
  unsigned r2 = pk2(fmaxf(v4, 0.f), fmaxf(v5, 0.f));
  unsigned r3 = pk2(fmaxf(v6, 0.f), fmaxf(v7, 0.f));
  plswap(r0, r2);
  plswap(r1, r3);
  uintx4 uv = {r0, r1, r2, r3};
  return __builtin_bit_cast(half8, uv);
}
__device__ __forceinline__ floatx16 zero16() {
  floatx16 z;
  #pragma unroll
  for (int i = 0; i < 16; ++i) z[i] = 0.f;
  return z;
}

// ---------------- prep: fragment-stream weights + BN fold + otab ----------------
__global__ void prep_kernel(const float* __restrict__ E,  const float* __restrict__ W1,
                            const float* __restrict__ b1, const float* __restrict__ W2,
                            const float* __restrict__ b2,
                            const float* __restrict__ rW1, const float* __restrict__ rb1,
                            const float* __restrict__ g1,  const float* __restrict__ be1,
                            const float* __restrict__ m1,  const float* __restrict__ v1,
                            const float* __restrict__ rW2, const float* __restrict__ rb2,
                            const float* __restrict__ g2,  const float* __restrict__ be2,
                            const float* __restrict__ m2,  const float* __restrict__ v2,
                            const float* __restrict__ rW3, char* __restrict__ ws)
{
  _Float16* tiles = (_Float16*)(ws + OFF_TILES);
  _Float16* w3t   = (_Float16*)(ws + OFF_W3);
  float*    t2o   = (float*)(ws + OFF_T2);
  float*    otab  = (float*)(ws + OFF_OTAB);

  const int NTI = 12 * 7168;   // chunk f16 elements
  const int NW3 = 2048;
  const int NT2 = 64;
  const int NOT = 116;
  const int NT  = NTI + NW3 + NT2 + NOT;

  for (int i = blockIdx.x * blockDim.x + threadIdx.x; i < NT; i += gridDim.x * blockDim.x) {
    int j = i;
    if (j < NTI) {
      const int ct = j / 7168;
      const int e  = j - ct * 7168;
      if (e < 3072) {                    // w1 frag f = nt*3+ks
        const int f  = e >> 9, li = (e >> 3) & 63, el = e & 7;
        const int nt = f / 3, ks = f - nt * 3;
        const int n  = ct * 64 + nt * 32 + (li & 31);
        const int k  = ks * 16 + (li >> 5) * 8 + el;
        float val = 0.f;
        const float S1 = g1[n] * rsqrtf(v1[n] + EPSV);
        if (k < 36)       val = rW1[(size_t)k * 768 + n] * S1;
        else if (k == 36) val = (rb1[n] - m1[n]) * S1 + be1[n];
        tiles[j] = (_Float16)val;
      } else {                           // w2 frag f = n2t*4+kc
        const int e2 = e - 3072;
        const int f  = e2 >> 9, li = (e2 >> 3) & 63, el = e2 & 7;
        const int n2t = f >> 2, kc = f & 3;
        const int n2 = n2t * 32 + (li & 31);
        const int k  = ct * 64 + kc * 16 + (li >> 5) * 8 + el;
        const float S2 = g2[n2] * rsqrtf(v2[n2] + EPSV);
        tiles[j] = (_Float16)(rW2[(size_t)k * 64 + n2] * S2);
      }
      continue;
    }
    j -= NTI;
    if (j < NW3) {                       // w3 frag f3 = kc (n3 padded 16->32)
      const int f3 = j >> 9, li = (j >> 3) & 63, el = j & 7;
      const int n3 = li & 31;
      const int k  = f3 * 16 + (li >> 5) * 8 + el;
      w3t[j] = (n3 < 16) ? (_Float16)rW3[(size_t)k * 16 + n3] : (_Float16)0.f;
      continue;
    }
    j -= NW3;
    if (j < NT2) {
      const float S2 = g2[j] * rsqrtf(v2[j] + EPSV);
      t2o[j] = (rb2[j] - m2[j]) * S2 + be2[j];
      continue;
    }
    j -= NT2;
    {                                    // otab[f][v] = full per-feature MLP
      const int f = j >> 2, v = j & 3;
      const float* ev  = E + ((f << 2) + v) * 12;
      const float* w1f = W1 + f * 144;
      float emb[12];
      #pragma unroll
      for (int d = 0; d < 12; ++d) emb[d] = ev[d];
      float acc_o = b2[f];
      #pragma unroll
      for (int ee = 0; ee < 12; ++ee) {
        float h = b1[f * 12 + ee];
        #pragma unroll
        for (int d = 0; d < 12; ++d) h = fmaf(emb[d], w1f[d * 12 + ee], h);
        h = fmaxf(h, 0.f);
        acc_o = fmaf(h, W2[f * 12 + ee], acc_o);
      }
      otab[f * 4 + v] = fmaxf(acc_o, 0.f);
    }
  }
}

__device__ __forceinline__ float feat_val(const float* xv, const float* otab, int c) {
  if (c < 7)  return xv[c];
  if (c < 36) return otab[(c - 7) * 4 + (int)xv[c]];
  if (c == 36) return 1.0f;              // BN1-shift constant column
  return 0.f;
}

// ------- main: 256 rows/block, 4 waves x 64 rows, ZERO LDS, barrier-free,
// ------- register-lean (no weight double-buffer; compiler pipelines) -------
__global__ __launch_bounds__(256, 2)
void fused_mfma_kernel(const float* __restrict__ x,
                       const float* __restrict__ rb3,
                       const float* __restrict__ rW4,
                       const float* __restrict__ rb4,
                       const char* __restrict__ ws,
                       float* __restrict__ out)
{
  const int t  = threadIdx.x;
  const int w  = t >> 6;
  const int l  = t & 63;
  const int lm = l & 31;
  const int hi = l >> 5;

  // bijective XCD swizzle (grid=512, 512%8==0): pure block-ID remap; each
  // block's computation depends only on b0 and writes disjoint rows, so any
  // bijection on [0,512) provably leaves the output bytes unchanged.
  const int nwg = gridDim.x;
  const int bid = (blockIdx.x & 7) * (nwg >> 3) + (blockIdx.x >> 3);
  const int b0 = bid * 256;

  // ---- Phase A: own row -> 24 packed words, entirely in registers ----
  unsigned wbits[24];
  {
    const float* xr = x + (size_t)(b0 + t) * 36;
    float xv[36];
    #pragma unroll
    for (int i = 0; i < 9; ++i) {
      float4 v = *(const float4*)(xr + 4 * i);
      xv[4 * i + 0] = v.x; xv[4 * i + 1] = v.y;
      xv[4 * i + 2] = v.z; xv[4 * i + 3] = v.w;
    }
    const float* otab = (const float*)(ws + OFF_OTAB);
    #pragma unroll
    for (int c2 = 0; c2 < 19; ++c2)
      wbits[c2] = pk2(feat_val(xv, otab, 2 * c2), feat_val(xv, otab, 2 * c2 + 1));
    #pragma unroll
    for (int c2 = 19; c2 < 24; ++c2) wbits[c2] = 0u;
  }

  // ---- xf via permlane: one swap yields both m-tile words (HW-verified R6/R7) ----
  half8 xf[2][3];
  #pragma unroll
  for (int ks = 0; ks < 3; ++ks) {
    unsigned w0[4], w1[4];
    #pragma unroll
    for (int q = 0; q < 4; ++q) {
      unsigned a = wbits[ks * 8 + q];
      unsigned b = wbits[ks * 8 + 4 + q];
      plswap(a, b);
      w0[q] = a; w1[q] = b;
    }
    uintx4 u0 = {w0[0], w0[1], w0[2], w0[3]};
    uintx4 u1 = {w1[0], w1[1], w1[2], w1[3]};
    xf[0][ks] = __builtin_bit_cast(half8, u0);
    xf[1][ks] = __builtin_bit_cast(half8, u1);
  }

  // lane-local fragment stream base
  const char* wsl = ws + (size_t)l * 16;

  floatx16 acc00 = zero16(), acc01 = zero16(), acc10 = zero16(), acc11 = zero16();

  #pragma unroll
  for (int ct = 0; ct < 12; ++ct) {
    const char* src = wsl + (size_t)ct * CHUNK_BYTES;
    // fragment loads for this chunk (L1/L2-hit after first touch); no reg dbuf —
    // compiler has headroom to pipeline, 2 waves/SIMD + setprio hide the rest
    half8 w1c[6], w2c[8];
    #pragma unroll
    for (int f = 0; f < 6; ++f)
      w1c[f] = *(const half8*)(src + f * 1024);
    #pragma unroll
    for (int f = 0; f < 8; ++f)
      w2c[f] = *(const half8*)(src + 6144 + f * 1024);

    __builtin_amdgcn_s_setprio(1);
    #pragma unroll
    for (int nt = 0; nt < 2; ++nt) {
      // GEMM1: h1^T half-chunk (32 n), both m-tiles
      floatx16 c1m0 = zero16(), c1m1 = zero16();
      #pragma unroll
      for (int ks = 0; ks < 3; ++ks) {
        half8 a = w1c[nt * 3 + ks];
        c1m0 = __builtin_amdgcn_mfma_f32_32x32x16_f16(a, xf[0][ks], c1m0, 0, 0, 0);
        c1m1 = __builtin_amdgcn_mfma_f32_32x32x16_f16(a, xf[1][ks], c1m1, 0, 0, 0);
      }
      // GEMM2: consume in-register (relu+pack+permlane), accumulate h2^T
      #pragma unroll
      for (int hf = 0; hf < 2; ++hf) {
        const int kc = nt * 2 + hf;
        const int b = hf * 8;
        half8 bf0 = mk_bfrag(c1m0[b+0], c1m0[b+1], c1m0[b+2], c1m0[b+3],
                             c1m0[b+4], c1m0[b+5], c1m0[b+6], c1m0[b+7]);
        half8 bf1 = mk_bfrag(c1m1[b+0], c1m1[b+1], c1m1[b+2], c1m1[b+3],
                             c1m1[b+4], c1m1[b+5], c1m1[b+6], c1m1[b+7]);
        acc00 = __builtin_amdgcn_mfma_f32_32x32x16_f16(w2c[0 * 4 + kc], bf0, acc00, 0, 0, 0);
        acc01 = __builtin_amdgcn_mfma_f32_32x32x16_f16(w2c[0 * 4 + kc], bf1, acc01, 0, 0, 0);
        acc10 = __builtin_amdgcn_mfma_f32_32x32x16_f16(w2c[1 * 4 + kc], bf0, acc10, 0, 0, 0);
        acc11 = __builtin_amdgcn_mfma_f32_32x32x16_f16(w2c[1 * 4 + kc], bf1, acc11, 0, 0, 0);
      }
    }
    __builtin_amdgcn_s_setprio(0);
  }

  // ---- Epilogue: +T2, relu, GEMM3 (w3 frags from L2), final dot + sigmoid ----
  const float* T2p = (const float*)(ws + OFF_T2);
  const _Float16* gW3 = (const _Float16*)(ws + OFF_W3);
  floatx16 c3a = zero16(), c3b = zero16();

  #pragma unroll
  for (int n2t = 0; n2t < 2; ++n2t) {
    float t2v[16];
    #pragma unroll
    for (int r = 0; r < 16; ++r)
      t2v[r] = T2p[n2t * 32 + (r & 3) + 8 * (r >> 2) + 4 * hi];
    const floatx16 am0 = n2t ? acc10 : acc00;
    const floatx16 am1 = n2t ? acc11 : acc01;
    float h0[16], h1v[16];
    #pragma unroll
    for (int r = 0; r < 16; ++r) {
      h0[r]  = fmaxf(am0[r] + t2v[r], 0.f);
      h1v[r] = fmaxf(am1[r] + t2v[r], 0.f);
    }
    #pragma unroll
    for (int hf = 0; hf < 2; ++hf) {
      const int kc = n2t * 2 + hf;
      const int b = hf * 8;
      half8 bf0 = mk_bfrag(h0[b+0], h0[b+1], h0[b+2], h0[b+3], h0[b+4], h0[b+5], h0[b+6], h0[b+7]);
      half8 bf1 = mk_bfrag(h1v[b+0], h1v[b+1], h1v[b+2], h1v[b+3], h1v[b+4], h1v[b+5], h1v[b+6], h1v[b+7]);
      half8 a3 = *(const half8*)&gW3[(kc * 64 + l) * 8];
      c3a = __builtin_amdgcn_mfma_f32_32x32x16_f16(a3, bf0, c3a, 0, 0, 0);
      c3b = __builtin_amdgcn_mfma_f32_32x32x16_f16(a3, bf1, c3b, 0, 0, 0);
    }
  }
  {
    float rb3v[8], rw4v[8];
    #pragma unroll
    for (int r = 0; r < 8; ++r) {
      const int n3 = (r & 3) + 8 * (r >> 2) + 4 * hi;
      rb3v[r] = rb3[n3];
      rw4v[r] = rW4[n3];
    }
    const float bb = rb4[0];
    float s0 = 0.f, s1 = 0.f;
    #pragma unroll
    for (int r = 0; r < 8; ++r) {
      s0 += fmaxf(c3a[r] + rb3v[r], 0.f) * rw4v[r];
      s1 += fmaxf(c3b[r] + rb3v[r], 0.f) * rw4v[r];
    }
    s0 += __shfl_xor(s0, 32, 64);
    s1 += __shfl_xor(s1, 32, 64);
    if (hi == 0) {
      out[b0 + (2 * w + 0) * 32 + lm] = 1.f / (1.f + expf(-(s0 + bb)));
      out[b0 + (2 * w + 1) * 32 + lm] = 1.f / (1.f + expf(-(s1 + bb)));
    }
  }
}

extern "C" void kernel_launch(void* const* d_in, const int* in_sizes, int n_in,
                              void* d_out, int out_size, void* d_ws, size_t ws_size,
                              hipStream_t stream) {
  const float* x   = (const float*)d_in[0];
  const float* E   = (const float*)d_in[1];
  const float* W1  = (const float*)d_in[2];
  const float* b1  = (const float*)d_in[3];
  const float* W2  = (const float*)d_in[4];
  const float* b2  = (const float*)d_in[5];
  const float* rW1 = (const float*)d_in[6];
  const float* rb1 = (const float*)d_in[7];
  const float* g1  = (const float*)d_in[8];
  const float* be1 = (const float*)d_in[9];
  const float* m1  = (const float*)d_in[10];
  const float* v1  = (const float*)d_in[11];
  const float* rW2 = (const float*)d_in[12];
  const float* rb2 = (const float*)d_in[13];
  const float* g2  = (const float*)d_in[14];
  const float* be2 = (const float*)d_in[15];
  const float* m2  = (const float*)d_in[16];
  const float* v2  = (const float*)d_in[17];
  const float* rW3 = (const float*)d_in[18];
  const float* rb3 = (const float*)d_in[19];
  const float* rW4 = (const float*)d_in[20];
  const float* rb4 = (const float*)d_in[21];
  float* out = (float*)d_out;
  char* ws = (char*)d_ws;

  prep_kernel<<<128, 256, 0, stream>>>(E, W1, b1, W2, b2,
                                       rW1, rb1, g1, be1, m1, v1,
                                       rW2, rb2, g2, be2, m2, v2,
                                       rW3, ws);

  const int B = in_sizes[0] / 36;     // 131072
  dim3 grid(B / 256), block(256);
  fused_mfma_kernel<<<grid, block, 0, stream>>>(x, rb3, rW4, rb4, ws, out);
}

// Round 6
// 32.659 us; speedup vs baseline: 1.0132x; 1.0113x over previous
//
#include <hip/hip_runtime.h>
#include <math.h>

typedef _Float16 half8 __attribute__((ext_vector_type(8)));
typedef float floatx16 __attribute__((ext_vector_type(16)));
typedef unsigned int uintx4 __attribute__((ext_vector_type(4)));

#define EPSV 1e-5f

// ---- workspace layout (bytes) ----
// 12 chunks of 14336 B, each = 6 w1-frags (6 KB) + 8 w2-frags (8 KB).
// Every frag = 64 lanes x 16 B in EXACT per-lane read order; main kernel
// reads fragments DIRECTLY from global (L1/L2-resident) — no LDS at all.
// R1-R4 lesson: every restructuring of the LANE data flow (LDS staging in 3
// forms, single-m-tile remap) produced deterministic wrong results; R5 proved
// env determinism (R0-verbatim + bijective swizzle passes bit-exact).
// Therefore: lane data flow is FROZEN at R0's. This round reorders only the
// TEMPORAL schedule (GEMM1s hoisted before GEMM2s) — values and accumulation
// order per lane/register are bit-identical.
#define CHUNK_BYTES 14336
#define OFF_TILES 0
#define OFF_W3    (12 * CHUNK_BYTES)     // 172032 : 4 frags x 1 KB (w3 padded to 32 rows)
#define OFF_T2    (OFF_W3 + 4096)        // 64 f32 folded BN2 shift
#define OFF_OTAB  (OFF_T2 + 256)         // 29x4 f32 embedding-MLP table

// manual RTE f16 pack — HW-verified R5-R7; do NOT swap for cvt_pkrtz (R8 ERRATA)
__device__ __forceinline__ unsigned pk2(float a, float b) {
  _Float16 ha = (_Float16)a, hb = (_Float16)b;
  return (unsigned)__builtin_bit_cast(unsigned short, ha) |
         ((unsigned)__builtin_bit_cast(unsigned short, hb) << 16);
}
__device__ __forceinline__ void plswap(unsigned &a, unsigned &b) {
  asm volatile("v_permlane32_swap_b32 %0, %1" : "+v"(a), "+v"(b));
}
// Build GEMM2 B-operand fragment (k-chunk word q = elems hi*8+2q,+1) from 8
// C-layout values (rows (r&3)+8*(r>>2)+4*hi), applying relu + f16 cast.
// HW-verified R5-R7.
__device__ __forceinline__ half8 mk_bfrag(float v0, float v1, float v2, float v3,
                                          float v4, float v5, float v6, float v7) {
  unsigned r0 = pk2(fmaxf(v0, 0.f), fmaxf(v1, 0.f));
  unsigned r1 = pk2(fmaxf(v2, 0.f), fmaxf(v3, 0.f));
  unsigned r2 = pk2(fmaxf(v4, 0.f), fmaxf(v5, 0.f));
  unsigned r3 = pk2(fmaxf(v6, 0.f), fmaxf(v7, 0.f));
  plswap(r0, r2);
  plswap(r1, r3);
  uintx4 uv = {r0, r1, r2, r3};
  return __builtin_bit_cast(half8, uv);
}
__device__ __forceinline__ floatx16 zero16() {
  floatx16 z;
  #pragma unroll
  for (int i = 0; i < 16; ++i) z[i] = 0.f;
  return z;
}

// ---------------- prep: fragment-stream weights + BN fold + otab ----------------
__global__ void prep_kernel(const float* __restrict__ E,  const float* __restrict__ W1,
                            const float* __restrict__ b1, const float* __restrict__ W2,
                            const float* __restrict__ b2,
                            const float* __restrict__ rW1, const float* __restrict__ rb1,
                            const float* __restrict__ g1,  const float* __restrict__ be1,
                            const float* __restrict__ m1,  const float* __restrict__ v1,
                            const float* __restrict__ rW2, const float* __restrict__ rb2,
                            const float* __restrict__ g2,  const float* __restrict__ be2,
                            const float* __restrict__ m2,  const float* __restrict__ v2,
                            const float* __restrict__ rW3, char* __restrict__ ws)
{
  _Float16* tiles = (_Float16*)(ws + OFF_TILES);
  _Float16* w3t   = (_Float16*)(ws + OFF_W3);
  float*    t2o   = (float*)(ws + OFF_T2);
  float*    otab  = (float*)(ws + OFF_OTAB);

  const int NTI = 12 * 7168;   // chunk f16 elements
  const int NW3 = 2048;
  const int NT2 = 64;
  const int NOT = 116;
  const int NT  = NTI + NW3 + NT2 + NOT;

  for (int i = blockIdx.x * blockDim.x + threadIdx.x; i < NT; i += gridDim.x * blockDim.x) {
    int j = i;
    if (j < NTI) {
      const int ct = j / 7168;
      const int e  = j - ct * 7168;
      if (e < 3072) {                    // w1 frag f = nt*3+ks
        const int f  = e >> 9, li = (e >> 3) & 63, el = e & 7;
        const int nt = f / 3, ks = f - nt * 3;
        const int n  = ct * 64 + nt * 32 + (li & 31);
        const int k  = ks * 16 + (li >> 5) * 8 + el;
        float val = 0.f;
        const float S1 = g1[n] * rsqrtf(v1[n] + EPSV);
        if (k < 36)       val = rW1[(size_t)k * 768 + n] * S1;
        else if (k == 36) val = (rb1[n] - m1[n]) * S1 + be1[n];
        tiles[j] = (_Float16)val;
      } else {                           // w2 frag f = n2t*4+kc
        const int e2 = e - 3072;
        const int f  = e2 >> 9, li = (e2 >> 3) & 63, el = e2 & 7;
        const int n2t = f >> 2, kc = f & 3;
        const int n2 = n2t * 32 + (li & 31);
        const int k  = ct * 64 + kc * 16 + (li >> 5) * 8 + el;
        const float S2 = g2[n2] * rsqrtf(v2[n2] + EPSV);
        tiles[j] = (_Float16)(rW2[(size_t)k * 64 + n2] * S2);
      }
      continue;
    }
    j -= NTI;
    if (j < NW3) {                       // w3 frag f3 = kc (n3 padded 16->32)
      const int f3 = j >> 9, li = (j >> 3) & 63, el = j & 7;
      const int n3 = li & 31;
      const int k  = f3 * 16 + (li >> 5) * 8 + el;
      w3t[j] = (n3 < 16) ? (_Float16)rW3[(size_t)k * 16 + n3] : (_Float16)0.f;
      continue;
    }
    j -= NW3;
    if (j < NT2) {
      const float S2 = g2[j] * rsqrtf(v2[j] + EPSV);
      t2o[j] = (rb2[j] - m2[j]) * S2 + be2[j];
      continue;
    }
    j -= NT2;
    {                                    // otab[f][v] = full per-feature MLP
      const int f = j >> 2, v = j & 3;
      const float* ev  = E + ((f << 2) + v) * 12;
      const float* w1f = W1 + f * 144;
      float emb[12];
      #pragma unroll
      for (int d = 0; d < 12; ++d) emb[d] = ev[d];
      float acc_o = b2[f];
      #pragma unroll
      for (int ee = 0; ee < 12; ++ee) {
        float h = b1[f * 12 + ee];
        #pragma unroll
        for (int d = 0; d < 12; ++d) h = fmaf(emb[d], w1f[d * 12 + ee], h);
        h = fmaxf(h, 0.f);
        acc_o = fmaf(h, W2[f * 12 + ee], acc_o);
      }
      otab[f * 4 + v] = fmaxf(acc_o, 0.f);
    }
  }
}

__device__ __forceinline__ float feat_val(const float* xv, const float* otab, int c) {
  if (c < 7)  return xv[c];
  if (c < 36) return otab[(c - 7) * 4 + (int)xv[c]];
  if (c == 36) return 1.0f;              // BN1-shift constant column
  return 0.f;
}

// ------- main: 256 rows/block, 4 waves x 64 rows, ZERO LDS, barrier-free.
// ------- Schedule: per chunk, BOTH GEMM1 half-chunks first (4 independent
// ------- MFMA chains), then all pack+GEMM2 (load-independent region) -------
__global__ __launch_bounds__(256, 2)
void fused_mfma_kernel(const float* __restrict__ x,
                       const float* __restrict__ rb3,
                       const float* __restrict__ rW4,
                       const float* __restrict__ rb4,
                       const char* __restrict__ ws,
                       float* __restrict__ out)
{
  const int t  = threadIdx.x;
  const int w  = t >> 6;
  const int l  = t & 63;
  const int lm = l & 31;
  const int hi = l >> 5;

  // bijective XCD swizzle (grid=512, 512%8==0): pure block-ID remap, output-
  // invariant (R5 verified bit-exact). Neutral perf; kept for L2 locality.
  const int nwg = gridDim.x;
  const int bid = (blockIdx.x & 7) * (nwg >> 3) + (blockIdx.x >> 3);
  const int b0 = bid * 256;

  // ---- Phase A: own row -> 24 packed words, entirely in registers ----
  unsigned wbits[24];
  {
    const float* xr = x + (size_t)(b0 + t) * 36;
    float xv[36];
    #pragma unroll
    for (int i = 0; i < 9; ++i) {
      float4 v = *(const float4*)(xr + 4 * i);
      xv[4 * i + 0] = v.x; xv[4 * i + 1] = v.y;
      xv[4 * i + 2] = v.z; xv[4 * i + 3] = v.w;
    }
    const float* otab = (const float*)(ws + OFF_OTAB);
    #pragma unroll
    for (int c2 = 0; c2 < 19; ++c2)
      wbits[c2] = pk2(feat_val(xv, otab, 2 * c2), feat_val(xv, otab, 2 * c2 + 1));
    #pragma unroll
    for (int c2 = 19; c2 < 24; ++c2) wbits[c2] = 0u;
  }

  // ---- xf via permlane: one swap yields both m-tile words (HW-verified R6/R7) ----
  half8 xf[2][3];
  #pragma unroll
  for (int ks = 0; ks < 3; ++ks) {
    unsigned w0[4], w1[4];
    #pragma unroll
    for (int q = 0; q < 4; ++q) {
      unsigned a = wbits[ks * 8 + q];
      unsigned b = wbits[ks * 8 + 4 + q];
      plswap(a, b);
      w0[q] = a; w1[q] = b;
    }
    uintx4 u0 = {w0[0], w0[1], w0[2], w0[3]};
    uintx4 u1 = {w1[0], w1[1], w1[2], w1[3]};
    xf[0][ks] = __builtin_bit_cast(half8, u0);
    xf[1][ks] = __builtin_bit_cast(half8, u1);
  }

  // lane-local fragment stream base
  const char* wsl = ws + (size_t)l * 16;

  floatx16 acc00 = zero16(), acc01 = zero16(), acc10 = zero16(), acc11 = zero16();

  #pragma unroll
  for (int ct = 0; ct < 12; ++ct) {
    const char* src = wsl + (size_t)ct * CHUNK_BYTES;
    // fragment loads for this chunk (L1/L2-hit after first touch)
    half8 w1c[6], w2c[8];
    #pragma unroll
    for (int f = 0; f < 6; ++f)
      w1c[f] = *(const half8*)(src + f * 1024);
    #pragma unroll
    for (int f = 0; f < 8; ++f)
      w2c[f] = *(const half8*)(src + 6144 + f * 1024);

    __builtin_amdgcn_s_setprio(1);
    // ---- Phase 1: both GEMM1 half-chunks up front — 4 independent
    // ---- 3-deep MFMA chains (vs 2 before), same values, same order per chain
    floatx16 p0m0 = zero16(), p0m1 = zero16();
    floatx16 p1m0 = zero16(), p1m1 = zero16();
    #pragma unroll
    for (int ks = 0; ks < 3; ++ks) {
      p0m0 = __builtin_amdgcn_mfma_f32_32x32x16_f16(w1c[ks],     xf[0][ks], p0m0, 0, 0, 0);
      p0m1 = __builtin_amdgcn_mfma_f32_32x32x16_f16(w1c[ks],     xf[1][ks], p0m1, 0, 0, 0);
      p1m0 = __builtin_amdgcn_mfma_f32_32x32x16_f16(w1c[3 + ks], xf[0][ks], p1m0, 0, 0, 0);
      p1m1 = __builtin_amdgcn_mfma_f32_32x32x16_f16(w1c[3 + ks], xf[1][ks], p1m1, 0, 0, 0);
    }
    // ---- Phase 2: pack + GEMM2, kc order 0,1,2,3 (accumulation order
    // ---- into each acc is IDENTICAL to the verified baseline)
    #pragma unroll
    for (int nt = 0; nt < 2; ++nt) {
      const floatx16 c1m0 = nt ? p1m0 : p0m0;   // compile-time select (rule #20)
      const floatx16 c1m1 = nt ? p1m1 : p0m1;
      #pragma unroll
      for (int hf = 0; hf < 2; ++hf) {
        const int kc = nt * 2 + hf;
        const int b = hf * 8;
        half8 bf0 = mk_bfrag(c1m0[b+0], c1m0[b+1], c1m0[b+2], c1m0[b+3],
                             c1m0[b+4], c1m0[b+5], c1m0[b+6], c1m0[b+7]);
        half8 bf1 = mk_bfrag(c1m1[b+0], c1m1[b+1], c1m1[b+2], c1m1[b+3],
                             c1m1[b+4], c1m1[b+5], c1m1[b+6], c1m1[b+7]);
        acc00 = __builtin_amdgcn_mfma_f32_32x32x16_f16(w2c[0 * 4 + kc], bf0, acc00, 0, 0, 0);
        acc01 = __builtin_amdgcn_mfma_f32_32x32x16_f16(w2c[0 * 4 + kc], bf1, acc01, 0, 0, 0);
        acc10 = __builtin_amdgcn_mfma_f32_32x32x16_f16(w2c[1 * 4 + kc], bf0, acc10, 0, 0, 0);
        acc11 = __builtin_amdgcn_mfma_f32_32x32x16_f16(w2c[1 * 4 + kc], bf1, acc11, 0, 0, 0);
      }
    }
    __builtin_amdgcn_s_setprio(0);
  }

  // ---- Epilogue: +T2, relu, GEMM3 (w3 frags from L2), final dot + sigmoid ----
  const float* T2p = (const float*)(ws + OFF_T2);
  const _Float16* gW3 = (const _Float16*)(ws + OFF_W3);
  floatx16 c3a = zero16(), c3b = zero16();

  #pragma unroll
  for (int n2t = 0; n2t < 2; ++n2t) {
    float t2v[16];
    #pragma unroll
    for (int r = 0; r < 16; ++r)
      t2v[r] = T2p[n2t * 32 + (r & 3) + 8 * (r >> 2) + 4 * hi];
    const floatx16 am0 = n2t ? acc10 : acc00;
    const floatx16 am1 = n2t ? acc11 : acc01;
    float h0[16], h1v[16];
    #pragma unroll
    for (int r = 0; r < 16; ++r) {
      h0[r]  = fmaxf(am0[r] + t2v[r], 0.f);
      h1v[r] = fmaxf(am1[r] + t2v[r], 0.f);
    }
    #pragma unroll
    for (int hf = 0; hf < 2; ++hf) {
      const int kc = n2t * 2 + hf;
      const int b = hf * 8;
      half8 bf0 = mk_bfrag(h0[b+0], h0[b+1], h0[b+2], h0[b+3], h0[b+4], h0[b+5], h0[b+6], h0[b+7]);
      half8 bf1 = mk_bfrag(h1v[b+0], h1v[b+1], h1v[b+2], h1v[b+3], h1v[b+4], h1v[b+5], h1v[b+6], h1v[b+7]);
      half8 a3 = *(const half8*)&gW3[(kc * 64 + l) * 8];
      c3a = __builtin_amdgcn_mfma_f32_32x32x16_f16(a3, bf0, c3a, 0, 0, 0);
      c3b = __builtin_amdgcn_mfma_f32_32x32x16_f16(a3, bf1, c3b, 0, 0, 0);
    }
  }
  {
    float rb3v[8], rw4v[8];
    #pragma unroll
    for (int r = 0; r < 8; ++r) {
      const int n3 = (r & 3) + 8 * (r >> 2) + 4 * hi;
      rb3v[r] = rb3[n3];
      rw4v[r] = rW4[n3];
    }
    const float bb = rb4[0];
    float s0 = 0.f, s1 = 0.f;
    #pragma unroll
    for (int r = 0; r < 8; ++r) {
      s0 += fmaxf(c3a[r] + rb3v[r], 0.f) * rw4v[r];
      s1 += fmaxf(c3b[r] + rb3v[r], 0.f) * rw4v[r];
    }
    s0 += __shfl_xor(s0, 32, 64);
    s1 += __shfl_xor(s1, 32, 64);
    if (hi == 0) {
      out[b0 + (2 * w + 0) * 32 + lm] = 1.f / (1.f + expf(-(s0 + bb)));
      out[b0 + (2 * w + 1) * 32 + lm] = 1.f / (1.f + expf(-(s1 + bb)));
    }
  }
}

extern "C" void kernel_launch(void* const* d_in, const int* in_sizes, int n_in,
                              void* d_out, int out_size, void* d_ws, size_t ws_size,
                              hipStream_t stream) {
  const float* x   = (const float*)d_in[0];
  const float* E   = (const float*)d_in[1];
  const float* W1  = (const float*)d_in[2];
  const float* b1  = (const float*)d_in[3];
  const float* W2  = (const float*)d_in[4];
  const float* b2  = (const float*)d_in[5];
  const float* rW1 = (const float*)d_in[6];
  const float* rb1 = (const float*)d_in[7];
  const float* g1  = (const float*)d_in[8];
  const float* be1 = (const float*)d_in[9];
  const float* m1  = (const float*)d_in[10];
  const float* v1  = (const float*)d_in[11];
  const float* rW2 = (const float*)d_in[12];
  const float* rb2 = (const float*)d_in[13];
  const float* g2  = (const float*)d_in[14];
  const float* be2 = (const float*)d_in[15];
  const float* m2  = (const float*)d_in[16];
  const float* v2  = (const float*)d_in[17];
  const float* rW3 = (const float*)d_in[18];
  const float* rb3 = (const float*)d_in[19];
  const float* rW4 = (const float*)d_in[20];
  const float* rb4 = (const float*)d_in[21];
  float* out = (float*)d_out;
  char* ws = (char*)d_ws;

  prep_kernel<<<128, 256, 0, stream>>>(E, W1, b1, W2, b2,
                                       rW1, rb1, g1, be1, m1, v1,
                                       rW2, rb2, g2, be2, m2, v2,
                                       rW3, ws);

  const int B = in_sizes[0] / 36;     // 131072
  dim3 grid(B / 256), block(256);
  fused_mfma_kernel<<<grid, block, 0, stream>>>(x, rb3, rW4, rb4, ws, out);
}